// Round 3
// baseline (486.665 us; speedup 1.0000x reference)
//
#include <hip/hip_runtime.h>
#include <math.h>

#define N_COLS 4096
#define EPSC 1e-12f
#define EPSD 1e-8f
#define MAXM 100.0f

__device__ __forceinline__ float wave_sum(float v) {
#pragma unroll
    for (int o = 32; o > 0; o >>= 1) v += __shfl_down(v, o, 64);
    return v;
}

// acc layout (doubles): 0 mag, 1 mean, 2 std, 3 phase, 4 corr, 5 js
__global__ __launch_bounds__(256) void pass1_kernel(
    const float* __restrict__ pre, const float* __restrict__ pim,
    const float* __restrict__ tre, const float* __restrict__ tim,
    float* __restrict__ Arow, float* __restrict__ Brow,
    float* __restrict__ pmc, float* __restrict__ tmc,
    double* __restrict__ acc, int cache_en)
{
    const int row = blockIdx.x;
    const int tid = threadIdx.x;
    const size_t base = (size_t)row * N_COLS;
    const float4* pr4 = (const float4*)(pre + base);
    const float4* pi4 = (const float4*)(pim + base);
    const float4* tr4 = (const float4*)(tre + base);
    const float4* ti4 = (const float4*)(tim + base);
    float4* pmc4 = cache_en ? (float4*)(pmc + base) : nullptr;
    float4* tmc4 = cache_en ? (float4*)(tmc + base) : nullptr;

    // 0 mag, 1 phase, 2 corr, 3 s_pm, 4 s_pm2, 5 s_tm, 6 s_tm2, 7 s_a, 8 s_b
    float s[9];
#pragma unroll
    for (int k = 0; k < 9; ++k) s[k] = 0.0f;

    for (int i = tid; i < N_COLS / 4; i += 256) {
        float4 X = pr4[i], Y = pi4[i], U = tr4[i], V = ti4[i];
        float4 PM, TM;
#pragma unroll
        for (int j = 0; j < 4; ++j) {
            float x = (&X.x)[j], y = (&Y.x)[j], u = (&U.x)[j], v = (&V.x)[j];
            float pmr = sqrtf(x * x + y * y);
            float tmr = sqrtf(u * u + v * v);
            (&PM.x)[j] = pmr;
            (&TM.x)[j] = tmr;
            float pm = fminf(fmaxf(pmr, EPSC), MAXM);
            float tm = fminf(fmaxf(tmr, EPSC), MAXM);
            float dm = pm - tm;
            s[0] += dm * dm;
            s[3] += pm; s[4] += pm * pm;
            s[5] += tm; s[6] += tm * tm;
            s[7] += pmr; s[8] += tmr;
            // wrapped phase diff = angle(p * conj(t)), p=(x+eps, y), t=(u+eps, v)
            float xr = x + EPSD, ur = u + EPSD;
            float re = xr * ur + y * v;
            float im = y * ur - xr * v;
            float pd = atan2f(im, re);
            s[1] += pd * pd;
            float pinv = 1.0f / (pm + EPSD);
            float tinv = 1.0f / (tm + EPSD);
            float dre = x * pinv - u * tinv;
            float dim_ = y * pinv - v * tinv;
            s[2] += dre * dre + dim_ * dim_;
        }
        if (cache_en) { pmc4[i] = PM; tmc4[i] = TM; }
    }

    // block reduction: wave-level shuffle, then LDS across 4 waves
    __shared__ float red[4][9];
    const int lane = tid & 63, wv = tid >> 6;
#pragma unroll
    for (int k = 0; k < 9; ++k) {
        float r = wave_sum(s[k]);
        if (lane == 0) red[wv][k] = r;
    }
    __syncthreads();
    if (tid == 0) {
        double t[9];
#pragma unroll
        for (int k = 0; k < 9; ++k)
            t[k] = (double)red[0][k] + (double)red[1][k] +
                   (double)red[2][k] + (double)red[3][k];
        atomicAdd(&acc[0], t[0]);
        atomicAdd(&acc[3], t[1]);
        atomicAdd(&acc[4], t[2]);
        const double Nd = (double)N_COLS;
        double pmean = t[3] / Nd, tmean = t[5] / Nd;
        double dmean = pmean - tmean;
        atomicAdd(&acc[1], dmean * dmean);
        double pvar = t[4] / Nd - pmean * pmean;
        double tvar = t[6] / Nd - tmean * tmean;
        pvar = pvar > 1e-12 ? pvar : 1e-12;
        tvar = tvar > 1e-12 ? tvar : 1e-12;
        double ds = sqrt(pvar) - sqrt(tvar);
        atomicAdd(&acc[2], ds * ds);
        Arow[row] = (float)(t[7] + Nd * (double)EPSC);
        Brow[row] = (float)(t[8] + Nd * (double)EPSC);
    }
}

__global__ __launch_bounds__(256) void pass2_kernel(
    const float* __restrict__ pre, const float* __restrict__ pim,
    const float* __restrict__ tre, const float* __restrict__ tim,
    const float* __restrict__ pmc, const float* __restrict__ tmc,
    const float* __restrict__ Arow, const float* __restrict__ Brow,
    double* __restrict__ acc, int cache_en)
{
    const int row = blockIdx.x;
    const int tid = threadIdx.x;
    const size_t base = (size_t)row * N_COLS;
    const float invA = 1.0f / Arow[row];
    const float invB = 1.0f / Brow[row];

    float s_js = 0.0f;
    if (cache_en) {
        const float4* a4 = (const float4*)(pmc + base);
        const float4* b4 = (const float4*)(tmc + base);
        for (int i = tid; i < N_COLS / 4; i += 256) {
            float4 A4 = a4[i], B4 = b4[i];
#pragma unroll
            for (int j = 0; j < 4; ++j) {
                float a = (&A4.x)[j] + EPSC;
                float b = (&B4.x)[j] + EPSC;
                float p = a * invA, q = b * invB;
                float t = 2.0f / (p + q);
                s_js += p * logf(p * t) + q * logf(q * t);
            }
        }
    } else {
        const float4* pr4 = (const float4*)(pre + base);
        const float4* pi4 = (const float4*)(pim + base);
        const float4* tr4 = (const float4*)(tre + base);
        const float4* ti4 = (const float4*)(tim + base);
        for (int i = tid; i < N_COLS / 4; i += 256) {
            float4 X = pr4[i], Y = pi4[i], U = tr4[i], V = ti4[i];
#pragma unroll
            for (int j = 0; j < 4; ++j) {
                float x = (&X.x)[j], y = (&Y.x)[j], u = (&U.x)[j], v = (&V.x)[j];
                float a = sqrtf(x * x + y * y) + EPSC;
                float b = sqrtf(u * u + v * v) + EPSC;
                float p = a * invA, q = b * invB;
                float t = 2.0f / (p + q);
                s_js += p * logf(p * t) + q * logf(q * t);
            }
        }
    }

    __shared__ float red[4];
    const int lane = tid & 63, wv = tid >> 6;
    float r = wave_sum(s_js);
    if (lane == 0) red[wv] = r;
    __syncthreads();
    if (tid == 0) {
        double t = (double)red[0] + (double)red[1] + (double)red[2] + (double)red[3];
        atomicAdd(&acc[5], 0.5 * t);  // js per row = 0.5*(kl_pm + kl_qm)
    }
}

__global__ void finalize_kernel(const double* __restrict__ acc,
                                float* __restrict__ out, int rows)
{
    const double Bd = (double)rows;
    const double BN = Bd * (double)N_COLS;
    double loss = 0.5  * (acc[0] / BN)   // MAG_W * mag_loss
                + 0.25 * (acc[1] / Bd)   // 0.5*MAG_W * mean_loss
                + 0.15 * (acc[2] / Bd)   // 0.3*MAG_W * std_loss
                + 0.5  * (acc[3] / BN)   // PHASE_W * phase_loss
                + 0.2  * (acc[4] / BN)   // 0.2 * corr_loss
                + 0.1  * (acc[5] / Bd);  // 0.1 * js_loss
    out[0] = (float)loss;
}

extern "C" void kernel_launch(void* const* d_in, const int* in_sizes, int n_in,
                              void* d_out, int out_size, void* d_ws, size_t ws_size,
                              hipStream_t stream) {
    const float* pre = (const float*)d_in[0];
    const float* pim = (const float*)d_in[1];
    const float* tre = (const float*)d_in[2];
    const float* tim = (const float*)d_in[3];
    float* out = (float*)d_out;
    const int rows = in_sizes[0] / N_COLS;

    char* ws = (char*)d_ws;
    double* acc = (double*)ws;                      // 6 doubles
    float* Arow = (float*)(ws + 64);
    float* Brow = Arow + rows;
    size_t cache_off = 64 + (size_t)2 * rows * sizeof(float);
    cache_off = (cache_off + 255) & ~(size_t)255;
    size_t cache_need = cache_off + 2ull * rows * N_COLS * sizeof(float);
    int cache_en = (ws_size >= cache_need) ? 1 : 0;
    float* pmc = cache_en ? (float*)(ws + cache_off) : nullptr;
    float* tmc = cache_en ? pmc + (size_t)rows * N_COLS : nullptr;

    hipMemsetAsync(d_ws, 0, 64, stream);
    pass1_kernel<<<rows, 256, 0, stream>>>(pre, pim, tre, tim, Arow, Brow,
                                           pmc, tmc, acc, cache_en);
    pass2_kernel<<<rows, 256, 0, stream>>>(pre, pim, tre, tim, pmc, tmc,
                                           Arow, Brow, acc, cache_en);
    finalize_kernel<<<1, 1, 0, stream>>>(acc, out, rows);
}

// Round 7
// 465.290 us; speedup vs baseline: 1.0459x; 1.0459x over previous
//
#include <hip/hip_runtime.h>
#include <math.h>

#define N_COLS 4096
#define EPSC 1e-12f
#define EPSD 1e-8f
#define MAXM 100.0f
#define LN2 0.6931471805599453

__device__ __forceinline__ float wave_sum(float v) {
#pragma unroll
    for (int o = 32; o > 0; o >>= 1) v += __shfl_down(v, o, 64);
    return v;
}

// atan2 via odd minimax poly on [0,1]; |err| ~1e-6 rad. Loss-level error
// ~1e-4 absolute, threshold is 5e-2 -> huge margin.
__device__ __forceinline__ float fast_atan2(float y, float x) {
    float ax = fabsf(x), ay = fabsf(y);
    float mx = fmaxf(ax, ay), mn = fminf(ax, ay);
    float t = mn * __builtin_amdgcn_rcpf(fmaxf(mx, 1e-37f));
    float s = t * t;
    float r = -0.01172120f;
    r = r * s + 0.05265332f;
    r = r * s - 0.11643287f;
    r = r * s + 0.19354346f;
    r = r * s - 0.33262347f;
    r = r * s + 0.99997726f;
    r = r * t;                                   // atan(mn/mx) in [0, pi/4]
    if (ay > ax) r = 1.5707963267948966f - r;
    if (x < 0.0f) r = 3.1415926535897931f - r;
    return copysignf(r, y);
}

// acc layout (doubles): 0 mag, 1 mean, 2 std, 3 phase, 4 corr, 5 js
__global__ __launch_bounds__(256) void fused_kernel(
    const float* __restrict__ pre, const float* __restrict__ pim,
    const float* __restrict__ tre, const float* __restrict__ tim,
    double* __restrict__ acc)
{
    const int row = blockIdx.x;
    const int tid = threadIdx.x;
    const size_t base = (size_t)row * N_COLS;
    const float4* pr4 = (const float4*)(pre + base);
    const float4* pi4 = (const float4*)(pim + base);
    const float4* tr4 = (const float4*)(tre + base);
    const float4* ti4 = (const float4*)(tim + base);

    // raw magnitudes cached in registers for the JS phase (statically indexed)
    float am[16], bm[16];
    // 0 mag, 1 phase, 2 corr, 3 s_pm, 4 s_pm2, 5 s_tm, 6 s_tm2, 7 s_a, 8 s_b
    float s[9];
#pragma unroll
    for (int k = 0; k < 9; ++k) s[k] = 0.0f;

    // two half-batches: 8 float4 loads issued up-front each (forced MLP),
    // then 8 elements of compute
#pragma unroll
    for (int h = 0; h < 2; ++h) {
        float4 X[2], Y[2], U[2], V[2];
#pragma unroll
        for (int i = 0; i < 2; ++i) {
            const int idx = tid + 256 * (2 * h + i);
            X[i] = pr4[idx];
            Y[i] = pi4[idx];
            U[i] = tr4[idx];
            V[i] = ti4[idx];
        }
#pragma unroll
        for (int i = 0; i < 2; ++i) {
#pragma unroll
            for (int j = 0; j < 4; ++j) {
                const int k = h * 8 + i * 4 + j;
                float x = (&X[i].x)[j], y = (&Y[i].x)[j];
                float u = (&U[i].x)[j], v = (&V[i].x)[j];
                float pmr = __builtin_amdgcn_sqrtf(x * x + y * y);
                float tmr = __builtin_amdgcn_sqrtf(u * u + v * v);
                am[k] = pmr;
                bm[k] = tmr;
                float pm = fminf(fmaxf(pmr, EPSC), MAXM);
                float tm = fminf(fmaxf(tmr, EPSC), MAXM);
                float dm = pm - tm;
                s[0] += dm * dm;
                s[3] += pm; s[4] += pm * pm;
                s[5] += tm; s[6] += tm * tm;
                s[7] += pmr; s[8] += tmr;
                // wrapped phase diff = angle(p * conj(t))
                float xr = x + EPSD, ur = u + EPSD;
                float re = xr * ur + y * v;
                float im = y * ur - xr * v;
                float pd = fast_atan2(im, re);
                s[1] += pd * pd;
                float pinv = __builtin_amdgcn_rcpf(pm + EPSD);
                float tinv = __builtin_amdgcn_rcpf(tm + EPSD);
                float dre = x * pinv - u * tinv;
                float dim_ = y * pinv - v * tinv;
                s[2] += dre * dre + dim_ * dim_;
            }
        }
    }

    // block reduction of the 9 sums
    __shared__ float red[4][9];
    __shared__ float bc[2];
    const int lane = tid & 63, wv = tid >> 6;
#pragma unroll
    for (int k = 0; k < 9; ++k) {
        float r = wave_sum(s[k]);
        if (lane == 0) red[wv][k] = r;
    }
    __syncthreads();
    if (tid == 0) {
        double t[9];
#pragma unroll
        for (int k = 0; k < 9; ++k)
            t[k] = (double)red[0][k] + (double)red[1][k] +
                   (double)red[2][k] + (double)red[3][k];
        atomicAdd(&acc[0], t[0]);
        atomicAdd(&acc[3], t[1]);
        atomicAdd(&acc[4], t[2]);
        const double Nd = (double)N_COLS;
        double pmean = t[3] / Nd, tmean = t[5] / Nd;
        double dmean = pmean - tmean;
        atomicAdd(&acc[1], dmean * dmean);
        double pvar = t[4] / Nd - pmean * pmean;
        double tvar = t[6] / Nd - tmean * tmean;
        pvar = pvar > 1e-12 ? pvar : 1e-12;
        tvar = tvar > 1e-12 ? tvar : 1e-12;
        double ds = sqrt(pvar) - sqrt(tvar);
        atomicAdd(&acc[2], ds * ds);
        double A = t[7] + Nd * (double)EPSC;   // sum of (raw + EPSC)
        double B = t[8] + Nd * (double)EPSC;
        bc[0] = (float)(1.0 / A);
        bc[1] = (float)(1.0 / B);
    }
    __syncthreads();

    // JS phase from register-cached raw magnitudes
    const float invA = bc[0], invB = bc[1];
    float sjs = 0.0f;  // accumulated in log2 units
#pragma unroll
    for (int k = 0; k < 16; ++k) {
        float a = am[k] + EPSC;
        float b = bm[k] + EPSC;
        float p = a * invA, q = b * invB;
        float rr = __builtin_amdgcn_rcpf(p + q);
        float l1 = __builtin_amdgcn_logf((2.0f * p) * rr);  // log2(2p/(p+q))
        float l2 = __builtin_amdgcn_logf((2.0f * q) * rr);
        sjs += p * l1 + q * l2;
    }
    {
        __shared__ float red2[4];
        float r = wave_sum(sjs);
        if (lane == 0) red2[wv] = r;
        __syncthreads();
        if (tid == 0) {
            double t = (double)red2[0] + (double)red2[1] +
                       (double)red2[2] + (double)red2[3];
            atomicAdd(&acc[5], 0.5 * LN2 * t);  // convert log2 -> ln, js=0.5*(kl+kl)
        }
    }
}

__global__ void finalize_kernel(const double* __restrict__ acc,
                                float* __restrict__ out, int rows)
{
    const double Bd = (double)rows;
    const double BN = Bd * (double)N_COLS;
    double loss = 0.5  * (acc[0] / BN)   // MAG_W * mag_loss
                + 0.25 * (acc[1] / Bd)   // 0.5*MAG_W * mean_loss
                + 0.15 * (acc[2] / Bd)   // 0.3*MAG_W * std_loss
                + 0.5  * (acc[3] / BN)   // PHASE_W * phase_loss
                + 0.2  * (acc[4] / BN)   // 0.2 * corr_loss
                + 0.1  * (acc[5] / Bd);  // 0.1 * js_loss
    out[0] = (float)loss;
}

extern "C" void kernel_launch(void* const* d_in, const int* in_sizes, int n_in,
                              void* d_out, int out_size, void* d_ws, size_t ws_size,
                              hipStream_t stream) {
    const float* pre = (const float*)d_in[0];
    const float* pim = (const float*)d_in[1];
    const float* tre = (const float*)d_in[2];
    const float* tim = (const float*)d_in[3];
    float* out = (float*)d_out;
    const int rows = in_sizes[0] / N_COLS;

    double* acc = (double*)d_ws;  // 6 doubles
    hipMemsetAsync(d_ws, 0, 64, stream);
    fused_kernel<<<rows, 256, 0, stream>>>(pre, pim, tre, tim, acc);
    finalize_kernel<<<1, 1, 0, stream>>>(acc, out, rows);
}

// Round 11
// 250.421 us; speedup vs baseline: 1.9434x; 1.8580x over previous
//
#include <hip/hip_runtime.h>
#include <math.h>

#define N_COLS 4096
#define EPSC 1e-12f
#define EPSD 1e-8f
#define MAXM 100.0f
#define LN2 0.6931471805599453

__device__ __forceinline__ float wave_sum(float v) {
#pragma unroll
    for (int o = 32; o > 0; o >>= 1) v += __shfl_down(v, o, 64);
    return v;
}

__device__ __forceinline__ double wave_sum_d(double v) {
#pragma unroll
    for (int o = 32; o > 0; o >>= 1) v += __shfl_down(v, o, 64);
    return v;
}

// atan2 via odd minimax poly; |err| ~1e-6 rad (loss-level ~1e-4 << 5e-2 threshold)
__device__ __forceinline__ float fast_atan2(float y, float x) {
    float ax = fabsf(x), ay = fabsf(y);
    float mx = fmaxf(ax, ay), mn = fminf(ax, ay);
    float t = mn * __builtin_amdgcn_rcpf(fmaxf(mx, 1e-37f));
    float s = t * t;
    float r = -0.01172120f;
    r = r * s + 0.05265332f;
    r = r * s - 0.11643287f;
    r = r * s + 0.19354346f;
    r = r * s - 0.33262347f;
    r = r * s + 0.99997726f;
    r = r * t;
    if (ay > ax) r = 1.5707963267948966f - r;
    if (x < 0.0f) r = 3.1415926535897931f - r;
    return copysignf(r, y);
}

// Per-row partials written to ws[row*8 + k], k: 0 mag, 1 dmean^2, 2 dstd^2,
// 3 phase, 4 corr, 5 js_row. 8-double stride = one 64B line per block (no
// false sharing, no atomics).
__global__ __launch_bounds__(256) void fused_kernel(
    const float* __restrict__ pre, const float* __restrict__ pim,
    const float* __restrict__ tre, const float* __restrict__ tim,
    double* __restrict__ ws)
{
    const int row = blockIdx.x;
    const int tid = threadIdx.x;
    const size_t base = (size_t)row * N_COLS;
    const float4* pr4 = (const float4*)(pre + base);
    const float4* pi4 = (const float4*)(pim + base);
    const float4* tr4 = (const float4*)(tre + base);
    const float4* ti4 = (const float4*)(tim + base);

    float am[16], bm[16];
    // 0 mag, 1 phase, 2 corr, 3 s_pm, 4 s_pm2, 5 s_tm, 6 s_tm2, 7 s_a, 8 s_b
    float s[9];
#pragma unroll
    for (int k = 0; k < 9; ++k) s[k] = 0.0f;

#pragma unroll
    for (int h = 0; h < 2; ++h) {
        float4 X[2], Y[2], U[2], V[2];
#pragma unroll
        for (int i = 0; i < 2; ++i) {
            const int idx = tid + 256 * (2 * h + i);
            X[i] = pr4[idx];
            Y[i] = pi4[idx];
            U[i] = tr4[idx];
            V[i] = ti4[idx];
        }
#pragma unroll
        for (int i = 0; i < 2; ++i) {
#pragma unroll
            for (int j = 0; j < 4; ++j) {
                const int k = h * 8 + i * 4 + j;
                float x = (&X[i].x)[j], y = (&Y[i].x)[j];
                float u = (&U[i].x)[j], v = (&V[i].x)[j];
                float pmr = __builtin_amdgcn_sqrtf(x * x + y * y);
                float tmr = __builtin_amdgcn_sqrtf(u * u + v * v);
                am[k] = pmr;
                bm[k] = tmr;
                float pm = fminf(fmaxf(pmr, EPSC), MAXM);
                float tm = fminf(fmaxf(tmr, EPSC), MAXM);
                float dm = pm - tm;
                s[0] += dm * dm;
                s[3] += pm; s[4] += pm * pm;
                s[5] += tm; s[6] += tm * tm;
                s[7] += pmr; s[8] += tmr;
                float xr = x + EPSD, ur = u + EPSD;
                float re = xr * ur + y * v;
                float im = y * ur - xr * v;
                float pd = fast_atan2(im, re);
                s[1] += pd * pd;
                float pinv = __builtin_amdgcn_rcpf(pm + EPSD);
                float tinv = __builtin_amdgcn_rcpf(tm + EPSD);
                float dre = x * pinv - u * tinv;
                float dim_ = y * pinv - v * tinv;
                s[2] += dre * dre + dim_ * dim_;
            }
        }
    }

    __shared__ float red[4][9];
    __shared__ float red2[4];
    const int lane = tid & 63, wv = tid >> 6;
#pragma unroll
    for (int k = 0; k < 9; ++k) {
        float r = wave_sum(s[k]);
        if (lane == 0) red[wv][k] = r;
    }
    __syncthreads();   // barrier 1: partials visible

    // replicated (every thread) f32 row sums for JS normalization — no tid0
    // serial section inside the barrier-critical path
    const float A = red[0][7] + red[1][7] + red[2][7] + red[3][7]
                  + (float)N_COLS * EPSC;
    const float B = red[0][8] + red[1][8] + red[2][8] + red[3][8]
                  + (float)N_COLS * EPSC;
    const float invA = __builtin_amdgcn_rcpf(A);
    const float invB = __builtin_amdgcn_rcpf(B);

    float sjs = 0.0f;  // in log2 units
#pragma unroll
    for (int k = 0; k < 16; ++k) {
        float a = am[k] + EPSC;
        float b = bm[k] + EPSC;
        float p = a * invA, q = b * invB;
        float rr = __builtin_amdgcn_rcpf(p + q);
        sjs += p * __builtin_amdgcn_logf((2.0f * p) * rr)
             + q * __builtin_amdgcn_logf((2.0f * q) * rr);
    }
    {
        float r = wave_sum(sjs);
        if (lane == 0) red2[wv] = r;
    }
    __syncthreads();   // barrier 2: js partials visible

    if (tid == 0) {    // f64 tail AFTER last barrier — other waves just exit
        double t[9];
#pragma unroll
        for (int k = 0; k < 9; ++k)
            t[k] = (double)red[0][k] + (double)red[1][k] +
                   (double)red[2][k] + (double)red[3][k];
        const double Nd = (double)N_COLS;
        double pmean = t[3] / Nd, tmean = t[5] / Nd;
        double dmean = pmean - tmean;
        double pvar = t[4] / Nd - pmean * pmean;
        double tvar = t[6] / Nd - tmean * tmean;
        pvar = pvar > 1e-12 ? pvar : 1e-12;
        tvar = tvar > 1e-12 ? tvar : 1e-12;
        double ds = sqrt(pvar) - sqrt(tvar);
        double js = 0.5 * LN2 * ((double)red2[0] + (double)red2[1] +
                                 (double)red2[2] + (double)red2[3]);
        double* slot = ws + (size_t)row * 8;
        slot[0] = t[0];          // mag sum
        slot[1] = dmean * dmean; // mean term
        slot[2] = ds * ds;       // std term
        slot[3] = t[1];          // phase sum
        slot[4] = t[2];          // corr sum
        slot[5] = js;            // js per row
    }
}

// One block reduces all per-row slots and emits the final loss.
__global__ __launch_bounds__(256) void reduce_kernel(
    const double* __restrict__ ws, float* __restrict__ out, int rows)
{
    const int tid = threadIdx.x;
    double t[6];
#pragma unroll
    for (int k = 0; k < 6; ++k) t[k] = 0.0;
    for (int r = tid; r < rows; r += 256) {
        const double* slot = ws + (size_t)r * 8;
#pragma unroll
        for (int k = 0; k < 6; ++k) t[k] += slot[k];
    }
    __shared__ double lds[4][6];
    const int lane = tid & 63, wv = tid >> 6;
#pragma unroll
    for (int k = 0; k < 6; ++k) {
        double r = wave_sum_d(t[k]);
        if (lane == 0) lds[wv][k] = r;
    }
    __syncthreads();
    if (tid == 0) {
        double f[6];
#pragma unroll
        for (int k = 0; k < 6; ++k)
            f[k] = lds[0][k] + lds[1][k] + lds[2][k] + lds[3][k];
        const double Bd = (double)rows;
        const double BN = Bd * (double)N_COLS;
        double loss = 0.5  * (f[0] / BN)
                    + 0.25 * (f[1] / Bd)
                    + 0.15 * (f[2] / Bd)
                    + 0.5  * (f[3] / BN)
                    + 0.2  * (f[4] / BN)
                    + 0.1  * (f[5] / Bd);
        out[0] = (float)loss;
    }
}

extern "C" void kernel_launch(void* const* d_in, const int* in_sizes, int n_in,
                              void* d_out, int out_size, void* d_ws, size_t ws_size,
                              hipStream_t stream) {
    const float* pre = (const float*)d_in[0];
    const float* pim = (const float*)d_in[1];
    const float* tre = (const float*)d_in[2];
    const float* tim = (const float*)d_in[3];
    float* out = (float*)d_out;
    const int rows = in_sizes[0] / N_COLS;

    double* ws = (double*)d_ws;   // rows * 8 doubles = 256 KB @ rows=4096
    fused_kernel<<<rows, 256, 0, stream>>>(pre, pim, tre, tim, ws);
    reduce_kernel<<<1, 256, 0, stream>>>(ws, out, rows);
}